// Round 13
// baseline (89.390 us; speedup 1.0000x reference)
//
#include <hip/hip_runtime.h>

#define SS 4096
#define DD 1024
#define HH 16

typedef float nfloat4 __attribute__((ext_vector_type(4)));
typedef __attribute__((ext_vector_type(8))) short bf16x8;
typedef __attribute__((ext_vector_type(4))) float f32x4;

__device__ __forceinline__ short f2bf(float f) {
  union { float f; unsigned u; } z; z.f = f;
  return (short)((z.u + 0x8000u) >> 16);    // round-half-up to bf16
}

// ---------------------------------------------------------------------------
// K0: pre-pack wq,wk into MFMA A-fragment order, bf16.
// wf[m][t][lane][e] = w_m[t*32 + (lane>>4)*8 + e][lane&15]   (m: 0=q, 1=k)
// ---------------------------------------------------------------------------
__global__ __launch_bounds__(256) void k_wfrag(
    const float* __restrict__ wq, const float* __restrict__ wk,
    short* __restrict__ wf)
{
  const int m = blockIdx.x;
  const float* __restrict__ w = m ? wk : wq;
  short* __restrict__ dst = wf + m * 16384;
  for (int p = threadIdx.x; p < 2048; p += 256) {   // p = t*64 + lane
    const int t = p >> 6, l = p & 63;
    const int kbase = t*32 + ((l >> 4) * 8), col = l & 15;
    short v[8];
#pragma unroll
    for (int e = 0; e < 8; ++e)
      v[e] = f2bf(w[(size_t)(kbase + e)*HH + col]);
    short* o = dst + (size_t)p * 8;
#pragma unroll
    for (int e = 0; e < 8; ++e) o[e] = v[e];
  }
}

// ---------------------------------------------------------------------------
// K1: kh = sigmoid(k@wk+bk) via MFMA, DMA-staged in TWO 32KB K-halves
// (16x512 fp32, pitch 516 -> 8-access/bank floor). LDS 33KB -> 4 blocks/CU:
// stage bursts of the 4 co-resident blocks interleave, keeping reads in
// flight continuously (kills the 50% phase-serial duty cycle of R12).
// Wave wid covers K-steps {4w..4w+3} U {16+4w..19+4w}; acc carries across.
// Also emits per-tile head-sums ksp[tile][16].
// ---------------------------------------------------------------------------
__global__ __launch_bounds__(256, 4) void k_kh(
    const float* __restrict__ k, const short* __restrict__ wf,
    const float* __restrict__ bk, float* __restrict__ kh,
    float* __restrict__ ksp)
{
  const int t = threadIdx.x;
  const int wid = t >> 6, lane = t & 63;
  const int s0 = blockIdx.x * 16;            // flat row over (B,S)
  const short* __restrict__ wfm = wf + 16384;   // k-half

  __shared__ float smem[16 * 516];           // 33,024 B

  bf16x8 afrag[8];
#pragma unroll
  for (int i = 0; i < 8; ++i) {
    const int st = (i < 4) ? (wid*4 + i) : (16 + wid*4 + (i - 4));
    afrag[i] = *(const bf16x8*)(wfm + (size_t)(st*64 + lane) * 8);
  }

  const int row = lane & 15, g = lane >> 4;
  f32x4 acc = {0.f, 0.f, 0.f, 0.f};
#pragma unroll
  for (int hf = 0; hf < 2; ++hf) {
    // DMA stage half hf: wave wid rows 4*wid..4*wid+3, 2 x 1KB segs per row.
    const int r0 = wid * 4;
#pragma unroll
    for (int rr = 0; rr < 4; ++rr) {
      const int r = r0 + rr;
      const float* gsrc = k + (size_t)(s0 + r)*DD + hf*512 + lane*4;
      float* lbase = smem + r*516;
#pragma unroll
      for (int sg = 0; sg < 2; ++sg) {
        __builtin_amdgcn_global_load_lds(
            (const __attribute__((address_space(1))) void*)(gsrc + sg*256),
            (__attribute__((address_space(3))) void*)(lbase + sg*256),
            16, 0, 0);
      }
    }
    __syncthreads();                         // half staged (vmcnt drained)
    const float* __restrict__ xrow = smem + row*516 + wid*128 + g*8;
#pragma unroll
    for (int tt = 0; tt < 4; ++tt) {
      const float4 lo = *(const float4*)(xrow + tt*32);
      const float4 hi = *(const float4*)(xrow + tt*32 + 4);
      bf16x8 bb;
      bb[0]=f2bf(lo.x); bb[1]=f2bf(lo.y); bb[2]=f2bf(lo.z); bb[3]=f2bf(lo.w);
      bb[4]=f2bf(hi.x); bb[5]=f2bf(hi.y); bb[6]=f2bf(hi.z); bb[7]=f2bf(hi.w);
      acc = __builtin_amdgcn_mfma_f32_16x16x32_bf16(afrag[hf*4+tt], bb, acc, 0, 0, 0);
    }
    __syncthreads();                         // reads done before next DMA
  }
  float* red = smem;                         // [4][64][4] alias (tile dead)
  *(f32x4*)&red[(wid*64 + lane)*4] = acc;
  __syncthreads();
  const int orow = t >> 4, ohead = t & 15;
  const int lane2 = ((ohead >> 2) << 4) + orow;
  const int j = ohead & 3;
  const float sacc = red[0*256 + lane2*4 + j] + red[1*256 + lane2*4 + j]
                   + red[2*256 + lane2*4 + j] + red[3*256 + lane2*4 + j];
  const float sig = 1.f/(1.f + __expf(-(sacc + bk[ohead])));
  kh[(size_t)(s0 + orow)*HH + ohead] = sig;
  __syncthreads();                           // red reads done
  smem[t] = sig;
  __syncthreads();
  if (t < 16) {
    float s = 0.f;
#pragma unroll
    for (int r = 0; r < 16; ++r) s += smem[r*16 + t];
    ksp[blockIdx.x*16 + t] = s;
  }
}

// ---------------------------------------------------------------------------
// K2: kvT partials (verbatim). Grid (32 schunk, 8 dchunk, 4 b).
// ---------------------------------------------------------------------------
__global__ __launch_bounds__(256, 8) void k_kvt(
    const float* __restrict__ v, const float* __restrict__ kh,
    float* __restrict__ part)
{
  const int schunk = blockIdx.x;   // 0..31
  const int dchunk = blockIdx.y;   // 0..7
  const int b = blockIdx.z;
  const int t = threadIdx.x;
  const int c = t & 31;
  const int hh2 = (t >> 5) & 1;
  const int g = t >> 6;            // 0..3
  const int d0 = dchunk*128 + c*4;
  float acc[8][4];
#pragma unroll
  for (int h = 0; h < 8; ++h) {
    acc[h][0] = 0.f; acc[h][1] = 0.f; acc[h][2] = 0.f; acc[h][3] = 0.f;
  }
#pragma unroll 2
  for (int jj = 0; jj < 32; ++jj) {
    const int s = (jj*4 + g)*32 + schunk;
    const size_t rb = (size_t)(b*SS + s);
    const float4 v4 = *(const float4*)(v + rb*DD + d0);
    const float4* khp = (const float4*)(kh + rb*HH) + hh2*2;
    const float4 k0 = khp[0], k1 = khp[1];
    const float kk[8] = {k0.x,k0.y,k0.z,k0.w, k1.x,k1.y,k1.z,k1.w};
#pragma unroll
    for (int h = 0; h < 8; ++h) {
      acc[h][0] = fmaf(kk[h], v4.x, acc[h][0]);
      acc[h][1] = fmaf(kk[h], v4.y, acc[h][1]);
      acc[h][2] = fmaf(kk[h], v4.z, acc[h][2]);
      acc[h][3] = fmaf(kk[h], v4.w, acc[h][3]);
    }
  }
  __shared__ float lds[4][2][128];
  const size_t pbase = (size_t)((b*8 + dchunk)*32 + schunk) * 2048;
#pragma unroll   // full unroll: acc indices stay compile-time
  for (int h = 0; h < 8; ++h) {
    *(float4*)&lds[g][hh2][c*4] =
        make_float4(acc[h][0], acc[h][1], acc[h][2], acc[h][3]);
    __syncthreads();
    {
      const int hh2r = t >> 7, dl = t & 127;
      const float sum = lds[0][hh2r][dl] + lds[1][hh2r][dl]
                      + lds[2][hh2r][dl] + lds[3][hh2r][dl];
      part[pbase + (hh2r*8 + h)*128 + dl] = sum;
    }
    __syncthreads();
  }
}

// ---------------------------------------------------------------------------
// K3: reduce part over 32 schunks -> kvt[b][h][1024]. 128 blocks, coalesced.
// ---------------------------------------------------------------------------
__global__ __launch_bounds__(256, 8) void k_red(
    const float* __restrict__ part, float* __restrict__ kvt)
{
  const int dchunk = blockIdx.x;
  const int b = blockIdx.y;
  const int hq = blockIdx.z;       // 0..3
  const int t = threadIdx.x;
  const size_t pb = (size_t)((b*8 + dchunk)*32) * 2048;
#pragma unroll
  for (int ho = 0; ho < 2; ++ho) {
    const int h = hq*4 + ho*2 + (t >> 7), dl = t & 127;
    float s = 0.f;
#pragma unroll 8
    for (int sc = 0; sc < 32; ++sc)
      s += part[pb + (size_t)sc*2048 + h*128 + dl];
    kvt[(size_t)(b*16 + h)*1024 + dchunk*128 + dl] = s;
  }
}

// ---------------------------------------------------------------------------
// K4: wv contraction, coalesced + parallel (verbatim). Grid (16,4,4).
// ---------------------------------------------------------------------------
__global__ __launch_bounds__(256, 4) void k_kv(
    const float* __restrict__ kvt, const float* __restrict__ wv,
    float* __restrict__ kvp)
{
  const int h = blockIdx.x;    // 0..15
  const int b = blockIdx.y;    // 0..3
  const int dq = blockIdx.z;   // 0..3
  const int t = threadIdx.x;
  const int w = t >> 6, lane = t & 63;
  __shared__ float kvs[256];
  __shared__ float red[256];
  kvs[t] = kvt[(size_t)(b*16 + h)*1024 + dq*256 + t];
  __syncthreads();
  const float* __restrict__ wp = wv + (size_t)(dq*256 + w*64)*DD + h*64 + lane;
  float acc = 0.f;
#pragma unroll 16
  for (int i = 0; i < 64; ++i)
    acc = fmaf(kvs[w*64 + i], wp[(size_t)i*DD], acc);
  red[t] = acc;
  __syncthreads();
  if (t < 64)
    kvp[((size_t)(b*16 + h)*4 + dq)*64 + t] =
        red[t] + red[64+t] + red[128+t] + red[192+t];
}

// ---------------------------------------------------------------------------
// K5: finalize kv (verbatim). Grid (4 b).
// ---------------------------------------------------------------------------
__global__ __launch_bounds__(256) void k_kvfin(
    const float* __restrict__ kvp, const float* __restrict__ ksp,
    const float* __restrict__ bv, float* __restrict__ kv)
{
  const int b = blockIdx.x;
  const int t = threadIdx.x;
  __shared__ float red[256];
  __shared__ float ksum[16];
  float s = 0.f;
#pragma unroll
  for (int m = 0; m < 16; ++m)
    s += ksp[b*4096 + m*256 + t];
  red[t] = s;
  __syncthreads();
  if (t < 16) {
    float ks = 0.f;
#pragma unroll
    for (int g = 0; g < 16; ++g) ks += red[g*16 + t];
    ksum[t] = ks;
  }
  __syncthreads();
#pragma unroll
  for (int j = 0; j < 4; ++j) {
    const int idx = j*256 + t;
    const int h = idx >> 6;
    const float* kp = kvp + (size_t)(b*16 + h)*256 + (idx & 63);
    kv[(size_t)b*1024 + idx] =
        kp[0] + kp[64] + kp[128] + kp[192] + ksum[h]*bv[idx];
  }
}

// ---------------------------------------------------------------------------
// K6: per (b,h): state = cumsum_h kv, then W2 = state @ wo rows (verbatim).
// ---------------------------------------------------------------------------
__global__ __launch_bounds__(256) void k_w2(
    const float* __restrict__ kv, const float* __restrict__ wo,
    float* __restrict__ W2)
{
  const int bh = blockIdx.x;
  const int b = bh >> 4, h = bh & 15;
  const int t = threadIdx.x;
  __shared__ float st[64];
  if (t < 64) {
    float s = 0.f;
    for (int hp = 0; hp <= h; ++hp) s += kv[(size_t)b*1024 + hp*64 + t];
    st[t] = s;
  }
  __syncthreads();
  const int d0 = t * 4;
  float4 acc = {0.f, 0.f, 0.f, 0.f};
#pragma unroll 4
  for (int dv = 0; dv < 64; ++dv) {
    const float sv = st[dv];
    const float4 w4 = *(const float4*)(wo + (size_t)(h*64 + dv)*DD + d0);
    acc.x = fmaf(sv, w4.x, acc.x);
    acc.y = fmaf(sv, w4.y, acc.y);
    acc.z = fmaf(sv, w4.z, acc.z);
    acc.w = fmaf(sv, w4.w, acc.w);
  }
  *(float4*)(W2 + (size_t)(b*HH + h)*DD + d0) = acc;
}

// ---------------------------------------------------------------------------
// K7: FUSED q-projection + output, half-K staged (33KB LDS -> 4 blocks/CU).
// Same pipeline as k_kh; then out = bo + qh @ W2[b] with nontemporal stores.
// ---------------------------------------------------------------------------
__global__ __launch_bounds__(256, 4) void k_qout(
    const float* __restrict__ q, const short* __restrict__ wf,
    const float* __restrict__ bq, const float* __restrict__ W2,
    const float* __restrict__ bo, float* __restrict__ out)
{
  const int t = threadIdx.x;
  const int wid = t >> 6, lane = t & 63;
  const int tile = blockIdx.x;               // 0..1023
  const int b = tile >> 8;                   // 256 tiles per batch
  const int s0 = tile * 16;

  __shared__ float smem[16 * 516];           // 33,024 B

  float4 w2[16];
  {
    const float* w2p = W2 + (size_t)(b*HH)*DD + t*4;
#pragma unroll
    for (int h = 0; h < 16; ++h) w2[h] = *(const float4*)(w2p + h*DD);
  }
  const float4 bo4 = *(const float4*)(bo + t*4);

  bf16x8 afrag[8];
#pragma unroll
  for (int i = 0; i < 8; ++i) {
    const int st = (i < 4) ? (wid*4 + i) : (16 + wid*4 + (i - 4));
    afrag[i] = *(const bf16x8*)(wf + (size_t)(st*64 + lane) * 8);  // q-half
  }

  const int row = lane & 15, g = lane >> 4;
  f32x4 acc = {0.f, 0.f, 0.f, 0.f};
#pragma unroll
  for (int hf = 0; hf < 2; ++hf) {
    const int r0 = wid * 4;
#pragma unroll
    for (int rr = 0; rr < 4; ++rr) {
      const int r = r0 + rr;
      const float* gsrc = q + (size_t)(s0 + r)*DD + hf*512 + lane*4;
      float* lbase = smem + r*516;
#pragma unroll
      for (int sg = 0; sg < 2; ++sg) {
        __builtin_amdgcn_global_load_lds(
            (const __attribute__((address_space(1))) void*)(gsrc + sg*256),
            (__attribute__((address_space(3))) void*)(lbase + sg*256),
            16, 0, 0);
      }
    }
    __syncthreads();
    const float* __restrict__ xrow = smem + row*516 + wid*128 + g*8;
#pragma unroll
    for (int tt = 0; tt < 4; ++tt) {
      const float4 lo = *(const float4*)(xrow + tt*32);
      const float4 hi = *(const float4*)(xrow + tt*32 + 4);
      bf16x8 bb;
      bb[0]=f2bf(lo.x); bb[1]=f2bf(lo.y); bb[2]=f2bf(lo.z); bb[3]=f2bf(lo.w);
      bb[4]=f2bf(hi.x); bb[5]=f2bf(hi.y); bb[6]=f2bf(hi.z); bb[7]=f2bf(hi.w);
      acc = __builtin_amdgcn_mfma_f32_16x16x32_bf16(afrag[hf*4+tt], bb, acc, 0, 0, 0);
    }
    __syncthreads();
  }
  float* red = smem;                         // [4][64][4] alias (tile dead)
  *(f32x4*)&red[(wid*64 + lane)*4] = acc;
  __syncthreads();
  {
    const int orow = t >> 4, ohead = t & 15;
    const int lane2 = ((ohead >> 2) << 4) + orow;
    const int j = ohead & 3;
    const float sacc = red[0*256 + lane2*4 + j] + red[1*256 + lane2*4 + j]
                     + red[2*256 + lane2*4 + j] + red[3*256 + lane2*4 + j];
    const float val = sacc + bq[ohead];
    smem[1024 + orow*16 + ohead] = 1.f/(1.f + __expf(-val));  // qs region
  }
  __syncthreads();

  const float* qs = smem + 1024;
#pragma unroll
  for (int r = 0; r < 16; ++r) {
    float4 o = bo4;
#pragma unroll
    for (int h = 0; h < 16; ++h) {
      const float qv = qs[r*16 + h];
      o.x = fmaf(qv, w2[h].x, o.x);
      o.y = fmaf(qv, w2[h].y, o.y);
      o.z = fmaf(qv, w2[h].z, o.z);
      o.w = fmaf(qv, w2[h].w, o.w);
    }
    nfloat4 ov = { o.x, o.y, o.z, o.w };
    nfloat4* dst = (nfloat4*)(out + (size_t)(s0 + r)*DD + t*4);
    __builtin_nontemporal_store(ov, dst);
  }
}

// ---------------------------------------------------------------------------
extern "C" void kernel_launch(void* const* d_in, const int* in_sizes, int n_in,
                              void* d_out, int out_size, void* d_ws, size_t ws_size,
                              hipStream_t stream)
{
  const float* q  = (const float*)d_in[0];
  const float* k  = (const float*)d_in[1];
  const float* v  = (const float*)d_in[2];
  const float* wq = (const float*)d_in[3];
  const float* bq = (const float*)d_in[4];
  const float* wk = (const float*)d_in[5];
  const float* bk = (const float*)d_in[6];
  const float* wv = (const float*)d_in[7];
  const float* bv = (const float*)d_in[8];
  const float* wo = (const float*)d_in[9];
  const float* bo = (const float*)d_in[10];
  float* out = (float*)d_out;
  float* ws  = (float*)d_ws;

  // ws layout (floats):
  // kh 262144 | kvt 65536 | kvp 16384 | ksp 16384 | kv 4096 | W2 65536 | wf
  float* kh  = ws;
  float* kvt = ws + 262144;
  float* kvp = ws + 327680;
  float* ksp = ws + 344064;
  float* kv  = ws + 360448;
  float* W2  = ws + 364544;
  short* wf  = (short*)(ws + 430080);
  // part (8 MB) at the FRONT of d_out: consumed by k_red, fully overwritten
  // by k_qout afterwards.
  float* part = out;

  hipLaunchKernelGGL(k_wfrag, dim3(2), dim3(256), 0, stream,
                     wq, wk, wf);
  hipLaunchKernelGGL(k_kh, dim3(1024), dim3(256), 0, stream,
                     k, wf, bk, kh, ksp);
  hipLaunchKernelGGL(k_kvt, dim3(32, 8, 4), dim3(256), 0, stream,
                     v, kh, part);
  hipLaunchKernelGGL(k_red, dim3(8, 4, 4), dim3(256), 0, stream,
                     part, kvt);
  hipLaunchKernelGGL(k_kv, dim3(16, 4, 4), dim3(256), 0, stream,
                     kvt, wv, kvp);
  hipLaunchKernelGGL(k_kvfin, dim3(4), dim3(256), 0, stream,
                     kvp, ksp, bv, kv);
  hipLaunchKernelGGL(k_w2, dim3(64), dim3(256), 0, stream,
                     kv, wo, W2);
  hipLaunchKernelGGL(k_qout, dim3(1024), dim3(256), 0, stream,
                     q, wf, bq, W2, bo, out);
}

// Round 14
// 88.986 us; speedup vs baseline: 1.0045x; 1.0045x over previous
//
#include <hip/hip_runtime.h>

#define SS 4096
#define DD 1024
#define HH 16
#define PITCH 260   // fp32 pitch: 260r mod 32 = 4r -> uniform 8-access/bank for b128

typedef float nfloat4 __attribute__((ext_vector_type(4)));
typedef __attribute__((ext_vector_type(8))) short bf16x8;
typedef __attribute__((ext_vector_type(4))) float f32x4;

__device__ __forceinline__ short f2bf(float f) {
  union { float f; unsigned u; } z; z.f = f;
  return (short)((z.u + 0x8000u) >> 16);    // round-half-up to bf16
}

// ---------------------------------------------------------------------------
// K0: pre-pack wq,wk into MFMA A-fragment order, bf16.
// wf[m][st][lane][e] = w_m[st*32 + (lane>>4)*8 + e][lane&15]   (m: 0=q, 1=k)
// ---------------------------------------------------------------------------
__global__ __launch_bounds__(256) void k_wfrag(
    const float* __restrict__ wq, const float* __restrict__ wk,
    short* __restrict__ wf)
{
  const int m = blockIdx.x;
  const float* __restrict__ w = m ? wk : wq;
  short* __restrict__ dst = wf + m * 16384;
  for (int p = threadIdx.x; p < 2048; p += 256) {   // p = st*64 + lane
    const int t = p >> 6, l = p & 63;
    const int kbase = t*32 + ((l >> 4) * 8), col = l & 15;
    short v[8];
#pragma unroll
    for (int e = 0; e < 8; ++e)
      v[e] = f2bf(w[(size_t)(kbase + e)*HH + col]);
    short* o = dst + (size_t)p * 8;
#pragma unroll
    for (int e = 0; e < 8; ++e) o[e] = v[e];
  }
}

// ---------------------------------------------------------------------------
// K1: kh = sigmoid(k@wk+bk). Quarter-K DMA pipeline with COUNTED vmcnt:
// two 16x260 buffers; stage q0,q1 up front; per quarter {vmcnt(4), barrier,
// 2 MFMA steps/wave, barrier, stage quarter+2}. Only the last quarter drains
// to vmcnt(0) -> the DMA queue never empties (kills the phase-serial stall).
// 34KB LDS -> 4 blocks/CU. Emits per-tile head-sums ksp[tile][16].
// ---------------------------------------------------------------------------
__global__ __launch_bounds__(256, 4) void k_kh(
    const float* __restrict__ k, const short* __restrict__ wf,
    const float* __restrict__ bk, float* __restrict__ kh,
    float* __restrict__ ksp)
{
  const int t = threadIdx.x;
  const int wid = t >> 6, lane = t & 63;
  const int s0 = blockIdx.x * 16;            // flat row over (B,S)
  const short* __restrict__ wfm = wf + 16384;   // k-half

  __shared__ float smem[2*16*PITCH + 256];   // 2 bufs + sig scratch
  float* const buf0 = smem;
  float* const buf1 = smem + 16*PITCH;

  // A-fragments (8 loads, oldest in vmcnt order — accounted in the counts)
  bf16x8 afrag[8];
#pragma unroll
  for (int i = 0; i < 8; ++i) {
    const int st = (i >> 1)*8 + wid*2 + (i & 1);
    afrag[i] = *(const bf16x8*)(wfm + (size_t)(st*64 + lane) * 8);
  }

  // stage quarter qd into bp: wave wid rows 4w..4w+3, 1KB DMA per row
#define STAGE_K(bp, qd)                                                      \
  {                                                                          \
    const int r0_ = wid*4;                                                   \
    _Pragma("unroll")                                                        \
    for (int rr_ = 0; rr_ < 4; ++rr_) {                                      \
      const int r_ = r0_ + rr_;                                              \
      __builtin_amdgcn_global_load_lds(                                      \
          (const __attribute__((address_space(1))) void*)                    \
              (k + (size_t)(s0 + r_)*DD + (qd)*256 + lane*4),                \
          (__attribute__((address_space(3))) void*)((bp) + r_*PITCH + lane*4), \
          16, 0, 0);                                                         \
    }                                                                        \
  }

  STAGE_K(buf0, 0);
  STAGE_K(buf1, 1);

  const int row = lane & 15, g = lane >> 4;
  f32x4 acc = {0.f, 0.f, 0.f, 0.f};
#pragma unroll
  for (int qd = 0; qd < 4; ++qd) {
    if (qd < 3) asm volatile("s_waitcnt vmcnt(4)" ::: "memory");
    else        asm volatile("s_waitcnt vmcnt(0)" ::: "memory");
    __builtin_amdgcn_s_barrier();            // current buffer ready (all waves)
    const float* bp = (qd & 1) ? buf1 : buf0;
    const float* xrow = bp + row*PITCH + wid*64 + g*8;
#pragma unroll
    for (int tt = 0; tt < 2; ++tt) {
      const float4 lo = *(const float4*)(xrow + tt*32);
      const float4 hi = *(const float4*)(xrow + tt*32 + 4);
      bf16x8 bb;
      bb[0]=f2bf(lo.x); bb[1]=f2bf(lo.y); bb[2]=f2bf(lo.z); bb[3]=f2bf(lo.w);
      bb[4]=f2bf(hi.x); bb[5]=f2bf(hi.y); bb[6]=f2bf(hi.z); bb[7]=f2bf(hi.w);
      acc = __builtin_amdgcn_mfma_f32_16x16x32_bf16(afrag[qd*2+tt], bb, acc, 0, 0, 0);
    }
    __builtin_amdgcn_s_barrier();            // all waves done reading buffer
    if (qd < 2) STAGE_K(((qd & 1) ? buf1 : buf0), qd + 2);
  }

  float* red = smem;                         // [4][64][4] alias (bufs dead)
  *(f32x4*)&red[(wid*64 + lane)*4] = acc;
  __syncthreads();
  const int orow = t >> 4, ohead = t & 15;
  const int lane2 = ((ohead >> 2) << 4) + orow;
  const int j = ohead & 3;
  const float sacc = red[0*256 + lane2*4 + j] + red[1*256 + lane2*4 + j]
                   + red[2*256 + lane2*4 + j] + red[3*256 + lane2*4 + j];
  const float sig = 1.f/(1.f + __expf(-(sacc + bk[ohead])));
  kh[(size_t)(s0 + orow)*HH + ohead] = sig;
  __syncthreads();                           // red reads done
  float* sg = smem + 2*16*PITCH;
  sg[t] = sig;
  __syncthreads();
  if (t < 16) {
    float s = 0.f;
#pragma unroll
    for (int r = 0; r < 16; ++r) s += sg[r*16 + t];
    ksp[blockIdx.x*16 + t] = s;
  }
}

// ---------------------------------------------------------------------------
// K2: kvT partials (verbatim R12). Grid (32 schunk, 8 dchunk, 4 b).
// ---------------------------------------------------------------------------
__global__ __launch_bounds__(256, 8) void k_kvt(
    const float* __restrict__ v, const float* __restrict__ kh,
    float* __restrict__ part)
{
  const int schunk = blockIdx.x;   // 0..31
  const int dchunk = blockIdx.y;   // 0..7
  const int b = blockIdx.z;
  const int t = threadIdx.x;
  const int c = t & 31;
  const int hh2 = (t >> 5) & 1;
  const int g = t >> 6;            // 0..3
  const int d0 = dchunk*128 + c*4;
  float acc[8][4];
#pragma unroll
  for (int h = 0; h < 8; ++h) {
    acc[h][0] = 0.f; acc[h][1] = 0.f; acc[h][2] = 0.f; acc[h][3] = 0.f;
  }
#pragma unroll 2
  for (int jj = 0; jj < 32; ++jj) {
    const int s = (jj*4 + g)*32 + schunk;
    const size_t rb = (size_t)(b*SS + s);
    const float4 v4 = *(const float4*)(v + rb*DD + d0);
    const float4* khp = (const float4*)(kh + rb*HH) + hh2*2;
    const float4 k0 = khp[0], k1 = khp[1];
    const float kk[8] = {k0.x,k0.y,k0.z,k0.w, k1.x,k1.y,k1.z,k1.w};
#pragma unroll
    for (int h = 0; h < 8; ++h) {
      acc[h][0] = fmaf(kk[h], v4.x, acc[h][0]);
      acc[h][1] = fmaf(kk[h], v4.y, acc[h][1]);
      acc[h][2] = fmaf(kk[h], v4.z, acc[h][2]);
      acc[h][3] = fmaf(kk[h], v4.w, acc[h][3]);
    }
  }
  __shared__ float lds[4][2][128];
  const size_t pbase = (size_t)((b*8 + dchunk)*32 + schunk) * 2048;
#pragma unroll   // full unroll: acc indices stay compile-time
  for (int h = 0; h < 8; ++h) {
    *(float4*)&lds[g][hh2][c*4] =
        make_float4(acc[h][0], acc[h][1], acc[h][2], acc[h][3]);
    __syncthreads();
    {
      const int hh2r = t >> 7, dl = t & 127;
      const float sum = lds[0][hh2r][dl] + lds[1][hh2r][dl]
                      + lds[2][hh2r][dl] + lds[3][hh2r][dl];
      part[pbase + (hh2r*8 + h)*128 + dl] = sum;
    }
    __syncthreads();
  }
}

// ---------------------------------------------------------------------------
// K3: reduce part over 32 schunks -> kvt[b][h][1024]. 128 blocks, coalesced.
// ---------------------------------------------------------------------------
__global__ __launch_bounds__(256, 8) void k_red(
    const float* __restrict__ part, float* __restrict__ kvt)
{
  const int dchunk = blockIdx.x;
  const int b = blockIdx.y;
  const int hq = blockIdx.z;       // 0..3
  const int t = threadIdx.x;
  const size_t pb = (size_t)((b*8 + dchunk)*32) * 2048;
#pragma unroll
  for (int ho = 0; ho < 2; ++ho) {
    const int h = hq*4 + ho*2 + (t >> 7), dl = t & 127;
    float s = 0.f;
#pragma unroll 8
    for (int sc = 0; sc < 32; ++sc)
      s += part[pb + (size_t)sc*2048 + h*128 + dl];
    kvt[(size_t)(b*16 + h)*1024 + dchunk*128 + dl] = s;
  }
}

// ---------------------------------------------------------------------------
// K4: wv contraction, coalesced + parallel (verbatim). Grid (16,4,4).
// ---------------------------------------------------------------------------
__global__ __launch_bounds__(256, 4) void k_kv(
    const float* __restrict__ kvt, const float* __restrict__ wv,
    float* __restrict__ kvp)
{
  const int h = blockIdx.x;    // 0..15
  const int b = blockIdx.y;    // 0..3
  const int dq = blockIdx.z;   // 0..3
  const int t = threadIdx.x;
  const int w = t >> 6, lane = t & 63;
  __shared__ float kvs[256];
  __shared__ float red[256];
  kvs[t] = kvt[(size_t)(b*16 + h)*1024 + dq*256 + t];
  __syncthreads();
  const float* __restrict__ wp = wv + (size_t)(dq*256 + w*64)*DD + h*64 + lane;
  float acc = 0.f;
#pragma unroll 16
  for (int i = 0; i < 64; ++i)
    acc = fmaf(kvs[w*64 + i], wp[(size_t)i*DD], acc);
  red[t] = acc;
  __syncthreads();
  if (t < 64)
    kvp[((size_t)(b*16 + h)*4 + dq)*64 + t] =
        red[t] + red[64+t] + red[128+t] + red[192+t];
}

// ---------------------------------------------------------------------------
// K5: finalize kv (verbatim). Grid (4 b).
// ---------------------------------------------------------------------------
__global__ __launch_bounds__(256) void k_kvfin(
    const float* __restrict__ kvp, const float* __restrict__ ksp,
    const float* __restrict__ bv, float* __restrict__ kv)
{
  const int b = blockIdx.x;
  const int t = threadIdx.x;
  __shared__ float red[256];
  __shared__ float ksum[16];
  float s = 0.f;
#pragma unroll
  for (int m = 0; m < 16; ++m)
    s += ksp[b*4096 + m*256 + t];
  red[t] = s;
  __syncthreads();
  if (t < 16) {
    float ks = 0.f;
#pragma unroll
    for (int g = 0; g < 16; ++g) ks += red[g*16 + t];
    ksum[t] = ks;
  }
  __syncthreads();
#pragma unroll
  for (int j = 0; j < 4; ++j) {
    const int idx = j*256 + t;
    const int h = idx >> 6;
    const float* kp = kvp + (size_t)(b*16 + h)*256 + (idx & 63);
    kv[(size_t)b*1024 + idx] =
        kp[0] + kp[64] + kp[128] + kp[192] + ksum[h]*bv[idx];
  }
}

// ---------------------------------------------------------------------------
// K6: per (b,h): state = cumsum_h kv, then W2 = state @ wo rows (verbatim).
// ---------------------------------------------------------------------------
__global__ __launch_bounds__(256) void k_w2(
    const float* __restrict__ kv, const float* __restrict__ wo,
    float* __restrict__ W2)
{
  const int bh = blockIdx.x;
  const int b = bh >> 4, h = bh & 15;
  const int t = threadIdx.x;
  __shared__ float st[64];
  if (t < 64) {
    float s = 0.f;
    for (int hp = 0; hp <= h; ++hp) s += kv[(size_t)b*1024 + hp*64 + t];
    st[t] = s;
  }
  __syncthreads();
  const int d0 = t * 4;
  float4 acc = {0.f, 0.f, 0.f, 0.f};
#pragma unroll 4
  for (int dv = 0; dv < 64; ++dv) {
    const float sv = st[dv];
    const float4 w4 = *(const float4*)(wo + (size_t)(h*64 + dv)*DD + d0);
    acc.x = fmaf(sv, w4.x, acc.x);
    acc.y = fmaf(sv, w4.y, acc.y);
    acc.z = fmaf(sv, w4.z, acc.z);
    acc.w = fmaf(sv, w4.w, acc.w);
  }
  *(float4*)(W2 + (size_t)(b*HH + h)*DD + d0) = acc;
}

// ---------------------------------------------------------------------------
// K7: FUSED q-projection + output, quarter-K counted-vmcnt pipeline (same as
// k_kh), then out = bo + qh @ W2[b]. w2/bo loads AFTER the final vmcnt(0) so
// they never perturb the counted waits. Nontemporal stores.
// ---------------------------------------------------------------------------
__global__ __launch_bounds__(256, 4) void k_qout(
    const float* __restrict__ q, const short* __restrict__ wf,
    const float* __restrict__ bq, const float* __restrict__ W2,
    const float* __restrict__ bo, float* __restrict__ out)
{
  const int t = threadIdx.x;
  const int wid = t >> 6, lane = t & 63;
  const int tile = blockIdx.x;               // 0..1023
  const int b = tile >> 8;                   // 256 tiles per batch
  const int s0 = tile * 16;

  __shared__ float smem[2*16*PITCH + 256];   // 2 bufs + qs
  float* const buf0 = smem;
  float* const buf1 = smem + 16*PITCH;

  bf16x8 afrag[8];
#pragma unroll
  for (int i = 0; i < 8; ++i) {
    const int st = (i >> 1)*8 + wid*2 + (i & 1);
    afrag[i] = *(const bf16x8*)(wf + (size_t)(st*64 + lane) * 8);  // q-half
  }

#define STAGE_Q(bp, qd)                                                      \
  {                                                                          \
    const int r0_ = wid*4;                                                   \
    _Pragma("unroll")                                                        \
    for (int rr_ = 0; rr_ < 4; ++rr_) {                                      \
      const int r_ = r0_ + rr_;                                              \
      __builtin_amdgcn_global_load_lds(                                      \
          (const __attribute__((address_space(1))) void*)                    \
              (q + (size_t)(s0 + r_)*DD + (qd)*256 + lane*4),                \
          (__attribute__((address_space(3))) void*)((bp) + r_*PITCH + lane*4), \
          16, 0, 0);                                                         \
    }                                                                        \
  }

  STAGE_Q(buf0, 0);
  STAGE_Q(buf1, 1);

  const int row = lane & 15, g = lane >> 4;
  f32x4 acc = {0.f, 0.f, 0.f, 0.f};
#pragma unroll
  for (int qd = 0; qd < 4; ++qd) {
    if (qd < 3) asm volatile("s_waitcnt vmcnt(4)" ::: "memory");
    else        asm volatile("s_waitcnt vmcnt(0)" ::: "memory");
    __builtin_amdgcn_s_barrier();
    const float* bp = (qd & 1) ? buf1 : buf0;
    const float* xrow = bp + row*PITCH + wid*64 + g*8;
#pragma unroll
    for (int tt = 0; tt < 2; ++tt) {
      const float4 lo = *(const float4*)(xrow + tt*32);
      const float4 hi = *(const float4*)(xrow + tt*32 + 4);
      bf16x8 bb;
      bb[0]=f2bf(lo.x); bb[1]=f2bf(lo.y); bb[2]=f2bf(lo.z); bb[3]=f2bf(lo.w);
      bb[4]=f2bf(hi.x); bb[5]=f2bf(hi.y); bb[6]=f2bf(hi.z); bb[7]=f2bf(hi.w);
      acc = __builtin_amdgcn_mfma_f32_16x16x32_bf16(afrag[qd*2+tt], bb, acc, 0, 0, 0);
    }
    __builtin_amdgcn_s_barrier();
    if (qd < 2) STAGE_Q(((qd & 1) ? buf1 : buf0), qd + 2);
  }

  // W2/bo loads after the last counted wait (never perturb vmcnt math);
  // their latency hides under the red/sigmoid phases below.
  float4 w2[16];
  {
    const float* w2p = W2 + (size_t)(b*HH)*DD + t*4;
#pragma unroll
    for (int h = 0; h < 16; ++h) w2[h] = *(const float4*)(w2p + h*DD);
  }
  const float4 bo4 = *(const float4*)(bo + t*4);

  float* red = smem;                         // [4][64][4] alias (bufs dead)
  *(f32x4*)&red[(wid*64 + lane)*4] = acc;
  __syncthreads();
  {
    const int orow = t >> 4, ohead = t & 15;
    const int lane2 = ((ohead >> 2) << 4) + orow;
    const int j = ohead & 3;
    const float sacc = red[0*256 + lane2*4 + j] + red[1*256 + lane2*4 + j]
                     + red[2*256 + lane2*4 + j] + red[3*256 + lane2*4 + j];
    const float val = sacc + bq[ohead];
    smem[2*16*PITCH + orow*16 + ohead] = 1.f/(1.f + __expf(-val));  // qs
  }
  __syncthreads();

  const float* qs = smem + 2*16*PITCH;
#pragma unroll
  for (int r = 0; r < 16; ++r) {
    float4 o = bo4;
#pragma unroll
    for (int h = 0; h < 16; ++h) {
      const float qv = qs[r*16 + h];
      o.x = fmaf(qv, w2[h].x, o.x);
      o.y = fmaf(qv, w2[h].y, o.y);
      o.z = fmaf(qv, w2[h].z, o.z);
      o.w = fmaf(qv, w2[h].w, o.w);
    }
    nfloat4 ov = { o.x, o.y, o.z, o.w };
    nfloat4* dst = (nfloat4*)(out + (size_t)(s0 + r)*DD + t*4);
    __builtin_nontemporal_store(ov, dst);
  }
}

// ---------------------------------------------------------------------------
extern "C" void kernel_launch(void* const* d_in, const int* in_sizes, int n_in,
                              void* d_out, int out_size, void* d_ws, size_t ws_size,
                              hipStream_t stream)
{
  const float* q  = (const float*)d_in[0];
  const float* k  = (const float*)d_in[1];
  const float* v  = (const float*)d_in[2];
  const float* wq = (const float*)d_in[3];
  const float* bq = (const float*)d_in[4];
  const float* wk = (const float*)d_in[5];
  const float* bk = (const float*)d_in[6];
  const float* wv = (const float*)d_in[7];
  const float* bv = (const float*)d_in[8];
  const float* wo = (const float*)d_in[9];
  const float* bo = (const float*)d_in[10];
  float* out = (float*)d_out;
  float* ws  = (float*)d_ws;

  // ws layout (floats):
  // kh 262144 | kvt 65536 | kvp 16384 | ksp 16384 | kv 4096 | W2 65536 | wf
  float* kh  = ws;
  float* kvt = ws + 262144;
  float* kvp = ws + 327680;
  float* ksp = ws + 344064;
  float* kv  = ws + 360448;
  float* W2  = ws + 364544;
  short* wf  = (short*)(ws + 430080);
  // part (8 MB) at the FRONT of d_out: consumed by k_red, fully overwritten
  // by k_qout afterwards.
  float* part = out;

  hipLaunchKernelGGL(k_wfrag, dim3(2), dim3(256), 0, stream,
                     wq, wk, wf);
  hipLaunchKernelGGL(k_kh, dim3(1024), dim3(256), 0, stream,
                     k, wf, bk, kh, ksp);
  hipLaunchKernelGGL(k_kvt, dim3(32, 8, 4), dim3(256), 0, stream,
                     v, kh, part);
  hipLaunchKernelGGL(k_red, dim3(8, 4, 4), dim3(256), 0, stream,
                     part, kvt);
  hipLaunchKernelGGL(k_kv, dim3(16, 4, 4), dim3(256), 0, stream,
                     kvt, wv, kvp);
  hipLaunchKernelGGL(k_kvfin, dim3(4), dim3(256), 0, stream,
                     kvp, ksp, bv, kv);
  hipLaunchKernelGGL(k_w2, dim3(64), dim3(256), 0, stream,
                     kv, wo, W2);
  hipLaunchKernelGGL(k_qout, dim3(1024), dim3(256), 0, stream,
                     q, wf, bq, W2, bo, out);
}